// Round 1
// baseline (623.051 us; speedup 1.0000x reference)
//
#include <hip/hip_runtime.h>
#include <hip/hip_bf16.h>

#define GD 64
#define GC 256

typedef unsigned short u16;
typedef unsigned int u32;
typedef short bf16x8 __attribute__((ext_vector_type(8)));
typedef float f32x4 __attribute__((ext_vector_type(4)));

__device__ __forceinline__ u16 f2bf_rne(float f) {
    u32 u = __builtin_bit_cast(u32, f);
    u = (u + 0x7FFFu + ((u >> 16) & 1u)) >> 16;
    return (u16)u;
}

__device__ __forceinline__ void unpack8(uint4 r, float* w) {
    u32 v[4] = {r.x, r.y, r.z, r.w};
#pragma unroll
    for (int i = 0; i < 4; i++) {
        w[2 * i]     = __builtin_bit_cast(float, v[i] << 16);
        w[2 * i + 1] = __builtin_bit_cast(float, v[i] & 0xFFFF0000u);
    }
}

// ---------------------------------------------------------------- init map
// map[cell] = point index or -1. Grid itself is NEVER initialized: empty
// cells are masked out of every read via this map.
__global__ __launch_bounds__(256) void init_map(uint4* __restrict__ m) {
    int i = blockIdx.x * 256 + threadIdx.x;        // 65536 uint4 = 1 MB
    uint4 v;
    v.x = v.y = v.z = v.w = 0xFFFFFFFFu;
    m[i] = v;
}

// ---------------------------------------------------------------- scatter
__global__ __launch_bounds__(256) void scatter_feats(const float* __restrict__ feats,
        const int* __restrict__ coords, u16* __restrict__ grid,
        int* __restrict__ map, int n) {
    int t = blockIdx.x * 256 + threadIdx.x;
    int i = t >> 5;
    if (i >= n) return;
    int c8 = (t & 31) << 3;
    int ix = coords[3 * i], iy = coords[3 * i + 1], iz = coords[3 * i + 2];
    int cell = (ix * GD + iy) * GD + iz;
    if ((t & 31) == 0) map[cell] = i;              // coords unique (permutation)
    const float4* src = (const float4*)(feats + (size_t)i * GC + c8);
    float4 a = src[0], b = src[1];
    u32 p0 = (u32)f2bf_rne(a.x) | ((u32)f2bf_rne(a.y) << 16);
    u32 p1 = (u32)f2bf_rne(a.z) | ((u32)f2bf_rne(a.w) << 16);
    u32 p2 = (u32)f2bf_rne(b.x) | ((u32)f2bf_rne(b.y) << 16);
    u32 p3 = (u32)f2bf_rne(b.z) | ((u32)f2bf_rne(b.w) << 16);
    *(uint4*)(grid + (size_t)cell * GC + c8) = make_uint4(p0, p1, p2, p3);
}

// ---------------------------------------------------------------- fused z+y pool
// Block = one x-slab x one channel-group (8 chunks = 64 ch). 512 threads:
// y = tid>>3 (64 rows), c = tid&7 (8 chunks of 8 ch). Per z-step:
//   - rolling 7-window over z in registers (masked loads: empty cells never
//     touch HBM, and the grid needs no -inf init)
//   - z-max -> bf16 -> LDS plane [64 y][8 c][8 ch] (double buffered)
//   - one __syncthreads, then 6-neighbor y-window from LDS (own value kept
//     in f32 registers), pack, store zy result in place.
// In-place is safe: thread writes only its own (y, chunk) column at z after
// having loaded z+3; cross-thread traffic goes through LDS only.
__global__ __launch_bounds__(512) void pool_zy(u16* __restrict__ grid,
        const int* __restrict__ map) {
    int x = blockIdx.x >> 2, cg = blockIdx.x & 3;
    int y = threadIdx.x >> 3, c = threadIdx.x & 7;
    int chunk = cg * 8 + c;
    const int* mrow = map + (x * GD + y) * GD;
    u16* p = grid + (size_t)((x * GD + y) * GD) * GC + chunk * 8;

    __shared__ __align__(16) u16 zp[2][64][8][8];   // 16 KB, double buffered

    float win[7][8];
#pragma unroll
    for (int s = 0; s < 7; s++)
#pragma unroll
        for (int cc = 0; cc < 8; cc++) win[s][cc] = -INFINITY;

#pragma unroll
    for (int t = 0; t < 3; t++) {                   // preload z=0..2 -> slots 3..5
        if (mrow[t] >= 0) {
            uint4 r = *(const uint4*)(p + (size_t)t * GC);
            unpack8(r, win[t + 3]);
        }
    }

#pragma unroll
    for (int z = 0; z < 64; z++) {
        int slot = (z + 6) % 7;                     // compile-time after unroll
        if (z + 3 < 64 && mrow[z + 3] >= 0) {
            uint4 r = *(const uint4*)(p + (size_t)(z + 3) * GC);
            unpack8(r, win[slot]);
        } else {
#pragma unroll
            for (int cc = 0; cc < 8; cc++) win[slot][cc] = -INFINITY;
        }

        // z-window max (kept in f32 regs for the dy==0 term of the y-pool)
        float mz[8];
#pragma unroll
        for (int cc = 0; cc < 8; cc++) {
            float m01 = fmaxf(win[0][cc], win[1][cc]);
            float m23 = fmaxf(win[2][cc], win[3][cc]);
            float m45 = fmaxf(win[4][cc], win[5][cc]);
            mz[cc] = fmaxf(fmaxf(m01, m23), fmaxf(m45, win[6][cc]));
        }
        // pack to bf16 (exact: max of bf16 values) -> LDS
        u32 q[4];
#pragma unroll
        for (int iq = 0; iq < 4; iq++) {
            u32 h0 = __builtin_bit_cast(u32, mz[2 * iq]);
            u32 h1 = __builtin_bit_cast(u32, mz[2 * iq + 1]);
            q[iq] = (h0 >> 16) | (h1 & 0xFFFF0000u);
        }
        *(uint4*)&zp[z & 1][y][c][0] = make_uint4(q[0], q[1], q[2], q[3]);
        __syncthreads();                             // one barrier per step (dbuf)

        // y-window: 6 neighbors from LDS, own term already in mz
#pragma unroll
        for (int dy = -3; dy <= 3; dy++) {
            if (dy == 0) continue;
            int yy = y + dy;
            if (yy >= 0 && yy < 64) {
                uint4 r = *(const uint4*)&zp[z & 1][yy][c][0];
                float w[8];
                unpack8(r, w);
#pragma unroll
                for (int cc = 0; cc < 8; cc++) mz[cc] = fmaxf(mz[cc], w[cc]);
            }
        }
        u32 o[4];
#pragma unroll
        for (int iq = 0; iq < 4; iq++) {
            u32 h0 = __builtin_bit_cast(u32, mz[2 * iq]);
            u32 h1 = __builtin_bit_cast(u32, mz[2 * iq + 1]);
            o[iq] = (h0 >> 16) | (h1 & 0xFFFF0000u);
        }
        *(uint4*)(p + (size_t)z * GC) = make_uint4(o[0], o[1], o[2], o[3]);
    }
}

// ---------------------------------------------------------------- x pool + compact
// Rolling 7-window along x; output written ONLY at occupied cells, directly
// into compacted pooled-feature rows P[i][256] (coalesced 512 B per row).
// Read 134 MB, write 51 MB (vs 134+134 before), and gemm1 loses its gather.
__global__ __launch_bounds__(256) void pool_x_compact(const u16* __restrict__ grid,
        const int* __restrict__ map, u16* __restrict__ P) {
    int chunk = threadIdx.x & 31;
    int L = blockIdx.x * 8 + (threadIdx.x >> 5);    // 0..4095 = y*64+z
    int y = L >> 6, z = L & 63;
    int cellBase = y * GD + z;                      // x = 0
    const u16* p = grid + (size_t)cellBase * GC + chunk * 8;
    size_t stepEl = (size_t)(GD * GD) * GC;

    float win[7][8];
#pragma unroll
    for (int s = 0; s < 7; s++)
#pragma unroll
        for (int cc = 0; cc < 8; cc++) win[s][cc] = -INFINITY;

#pragma unroll
    for (int t = 0; t < 3; t++) {                   // zy grid is valid everywhere
        uint4 r = *(const uint4*)(p + (size_t)t * stepEl);
        unpack8(r, win[t + 3]);
    }

#pragma unroll
    for (int x = 0; x < 64; x++) {
        int slot = (x + 6) % 7;
        if (x + 3 < 64) {
            uint4 r = *(const uint4*)(p + (size_t)(x + 3) * stepEl);
            unpack8(r, win[slot]);
        } else {
#pragma unroll
            for (int cc = 0; cc < 8; cc++) win[slot][cc] = -INFINITY;
        }
        int mi = map[cellBase + x * GD * GD];       // wave-uniform broadcast
        if (mi >= 0) {
            u32 q[4];
#pragma unroll
            for (int iq = 0; iq < 4; iq++) {
                u32 halves[2];
#pragma unroll
                for (int hh = 0; hh < 2; hh++) {
                    int cc = 2 * iq + hh;
                    float m01 = fmaxf(win[0][cc], win[1][cc]);
                    float m23 = fmaxf(win[2][cc], win[3][cc]);
                    float m45 = fmaxf(win[4][cc], win[5][cc]);
                    float m = fmaxf(fmaxf(m01, m23), fmaxf(m45, win[6][cc]));
                    halves[hh] = __builtin_bit_cast(u32, m);
                }
                q[iq] = (halves[0] >> 16) | (halves[1] & 0xFFFF0000u);
            }
            *(uint4*)(P + (size_t)mi * GC + chunk * 8) = make_uint4(q[0], q[1], q[2], q[3]);
        }
    }
}

// ---------------------------------------------------------------- weight prep
__global__ __launch_bounds__(256) void prep_weights(const float* __restrict__ W1,
        const float* __restrict__ W2, u16* __restrict__ img1, u16* __restrict__ img2) {
    int t = blockIdx.x * 256 + threadIdx.x;   // 0..65535
    if (t < 32768) {
        int h = t >> 14, nn = (t >> 8) & 63, chunk = (t >> 3) & 31, j = t & 7;
        int k = chunk * 8 + j;
        img1[(h << 14) + nn * 256 + (((chunk ^ (nn & 7)) << 3) | j)] =
            f2bf_rne(W1[k * 128 + h * 64 + nn]);
    } else {
        int t2 = t - 32768;
        int h = t2 >> 14, nn = (t2 >> 7) & 127, chunk = (t2 >> 3) & 15, j = t2 & 7;
        int k = chunk * 8 + j;
        img2[(h << 14) + nn * 128 + (((chunk ^ (nn & 7)) << 3) | j)] =
            f2bf_rne(W2[k * 256 + h * 128 + nn]);
    }
}

// ---------------------------------------------------------------- GEMM1 (half-N)
// Reads compacted P rows (coalesced) instead of gathering grid cells.
__global__ __launch_bounds__(256, 4) void gemm1_kernel(const u16* __restrict__ P,
        const u16* __restrict__ img1, u16* __restrict__ H, int n, int nrb) {
    __shared__ __align__(16) u16 w1t[64 * 256];   // 32768 B; reused as hbuf
    int h = blockIdx.x >= nrb;
    int rb = blockIdx.x - (h ? nrb : 0);
    int tid = threadIdx.x;

    const uint4* src = (const uint4*)(img1 + (h << 14));
    uint4* dst = (uint4*)w1t;
#pragma unroll
    for (int i = 0; i < 8; i++) dst[i * 256 + tid] = src[i * 256 + tid];

    int wave = tid >> 6, lane = tid & 63, m16 = lane & 15, quad = lane >> 4;
    int row_a = rb * 64 + wave * 16 + m16;
    int ra = min(row_a, n - 1);
    const u16* yrow = P + (size_t)ra * GC;
    bf16x8 afr[8];
#pragma unroll
    for (int kk = 0; kk < 8; kk++)
        afr[kk] = *(const bf16x8*)(yrow + kk * 32 + quad * 8);
    __syncthreads();

    f32x4 acc[4];
#pragma unroll
    for (int t = 0; t < 4; t++) acc[t] = (f32x4){0.f, 0.f, 0.f, 0.f};
#pragma unroll
    for (int kk = 0; kk < 8; kk++) {
        int chunk = kk * 4 + quad;
#pragma unroll
        for (int t = 0; t < 4; t++) {
            int r = t * 16 + m16;
            bf16x8 b = *(const bf16x8*)&w1t[r * 256 + ((chunk ^ (r & 7)) << 3)];
            acc[t] = __builtin_amdgcn_mfma_f32_16x16x32_bf16(afr[kk], b, acc[t], 0, 0, 0);
        }
    }
    __syncthreads();   // w1t dead; reuse as hbuf [row(64)][c8^swz][j]

    u16* hbuf = w1t;
#pragma unroll
    for (int t = 0; t < 4; t++) {
        int col = t * 16 + m16;
        int c8 = col >> 3, j = col & 7;
#pragma unroll
        for (int rr = 0; rr < 4; rr++) {
            int row_l = wave * 16 + quad * 4 + rr;
            float hv = fmaxf(acc[t][rr], 0.0f);
            hbuf[row_l * 64 + (((c8 ^ (row_l & 7)) << 3) | j)] = f2bf_rne(hv);
        }
    }
    __syncthreads();
#pragma unroll
    for (int i = 0; i < 2; i++) {
        int cid = i * 256 + tid;            // 0..511 chunks of 8
        int row_l = cid >> 3, c8 = cid & 7;
        int grow = rb * 64 + row_l;
        if (grow < n) {
            bf16x8 v = *(const bf16x8*)&hbuf[row_l * 64 + ((c8 ^ (row_l & 7)) << 3)];
            *(bf16x8*)&H[(size_t)grow * 128 + h * 64 + c8 * 8] = v;
        }
    }
}

// ---------------------------------------------------------------- GEMM2 (half-N)
__global__ __launch_bounds__(256, 4) void gemm2_kernel(const u16* __restrict__ H,
        const u16* __restrict__ img2, const float* __restrict__ feats,
        float* __restrict__ out, int n, int nrb) {
    __shared__ __align__(16) char smem[64 * 140 * 4];   // 35840 B
    u16* w2t = (u16*)smem;          // 32768 B used
    float* zbuf = (float*)smem;     // 64 x 140
    int h = blockIdx.x >= nrb;
    int rb = blockIdx.x - (h ? nrb : 0);
    int tid = threadIdx.x;

    const uint4* src = (const uint4*)(img2 + (h << 14));
    uint4* dst = (uint4*)w2t;
#pragma unroll
    for (int i = 0; i < 8; i++) dst[i * 256 + tid] = src[i * 256 + tid];

    int wave = tid >> 6, lane = tid & 63, m16 = lane & 15, quad = lane >> 4;
    int row_a = rb * 64 + wave * 16 + m16;
    int ra = min(row_a, n - 1);
    const u16* hrow = H + (size_t)ra * 128;
    bf16x8 afr[4];
#pragma unroll
    for (int kk = 0; kk < 4; kk++)
        afr[kk] = *(const bf16x8*)(hrow + kk * 32 + quad * 8);
    __syncthreads();

    f32x4 acc[8];
#pragma unroll
    for (int t = 0; t < 8; t++) acc[t] = (f32x4){0.f, 0.f, 0.f, 0.f};
#pragma unroll
    for (int kk = 0; kk < 4; kk++) {
        int chunk = kk * 4 + quad;
#pragma unroll
        for (int t = 0; t < 8; t++) {
            int nn = t * 16 + m16;
            bf16x8 b = *(const bf16x8*)&w2t[nn * 128 + ((chunk ^ (nn & 7)) << 3)];
            acc[t] = __builtin_amdgcn_mfma_f32_16x16x32_bf16(afr[kk], b, acc[t], 0, 0, 0);
        }
    }
    __syncthreads();   // w2t dead; write logits into zbuf

#pragma unroll
    for (int t = 0; t < 8; t++) {
        int col = t * 16 + m16;
#pragma unroll
        for (int rr = 0; rr < 4; rr++) {
            int row_l = wave * 16 + quad * 4 + rr;
            zbuf[row_l * 140 + col] = acc[t][rr];
        }
    }
    __syncthreads();
#pragma unroll
    for (int i = 0; i < 8; i++) {
        int f = i * 256 + tid;              // 0..2047 float4s
        int row_l = f >> 5, c4 = f & 31;
        int grow = rb * 64 + row_l;
        if (grow < n) {
            f32x4 z = *(const f32x4*)&zbuf[row_l * 140 + c4 * 4];
            size_t o = (size_t)grow * 256 + h * 128 + c4 * 4;
            f32x4 ft = *(const f32x4*)&feats[o];
            f32x4 r;
#pragma unroll
            for (int c = 0; c < 4; c++)
                r[c] = ft[c] / (1.0f + __expf(-z[c]));
            *(f32x4*)&out[o] = r;
        }
    }
}

// ---------------------------------------------------------------- launch
extern "C" void kernel_launch(void* const* d_in, const int* in_sizes, int n_in,
                              void* d_out, int out_size, void* d_ws, size_t ws_size,
                              hipStream_t stream) {
    const float* feats = (const float*)d_in[0];
    const int* coords = (const int*)d_in[1];
    const float* W1 = (const float*)d_in[2];
    const float* W2 = (const float*)d_in[3];
    float* out = (float*)d_out;

    int n = in_sizes[1] / 3;                       // 100000 points

    size_t grid_bytes = (size_t)GD * GD * GD * GC * 2;          // 134,217,728
    size_t P_bytes = (size_t)n * GC * 2;                        //  51,200,000
    size_t H_bytes = (size_t)n * 128 * 2;                       //  25,600,000
    u16* grid = (u16*)d_ws;                                     // NOT initialized
    u16* P = (u16*)((char*)d_ws + grid_bytes);
    u16* H = (u16*)((char*)d_ws + grid_bytes + P_bytes);
    int* map = (int*)((char*)d_ws + grid_bytes + P_bytes + H_bytes);
    u16* img1 = (u16*)((char*)map + (size_t)GD * GD * GD * 4);  // +1 MB
    u16* img2 = img1 + 32768;

    init_map<<<256, 256, 0, stream>>>((uint4*)map);
    prep_weights<<<256, 256, 0, stream>>>(W1, W2, img1, img2);
    scatter_feats<<<(n * 32 + 255) / 256, 256, 0, stream>>>(feats, coords, grid, map, n);

    pool_zy<<<256, 512, 0, stream>>>(grid, map);          // fused z+y, in place
    pool_x_compact<<<512, 256, 0, stream>>>(grid, map, P); // x pool -> compact rows

    int nrb = (n + 63) / 64;
    gemm1_kernel<<<2 * nrb, 256, 0, stream>>>(P, img1, H, n, nrb);
    gemm2_kernel<<<2 * nrb, 256, 0, stream>>>(H, img2, feats, out, n, nrb);
}

// Round 2
// 448.196 us; speedup vs baseline: 1.3901x; 1.3901x over previous
//
#include <hip/hip_runtime.h>
#include <hip/hip_bf16.h>

#define GD 64
#define GC 256

typedef unsigned short u16;
typedef unsigned int u32;
typedef short bf16x8 __attribute__((ext_vector_type(8)));
typedef float f32x4 __attribute__((ext_vector_type(4)));

__device__ __forceinline__ u16 f2bf_rne(float f) {
    u32 u = __builtin_bit_cast(u32, f);
    u = (u + 0x7FFFu + ((u >> 16) & 1u)) >> 16;
    return (u16)u;
}

// round f32 to the exact bf16-representable value (RNE) — keeps pool numerics
// bit-identical to the scatter-then-pool pipeline.
__device__ __forceinline__ float bfval(float f) {
    u32 u = __builtin_bit_cast(u32, f);
    u = (u + 0x7FFFu + ((u >> 16) & 1u)) & 0xFFFF0000u;
    return __builtin_bit_cast(float, u);
}

__device__ __forceinline__ void unpack8(uint4 r, float* w) {
    u32 v[4] = {r.x, r.y, r.z, r.w};
#pragma unroll
    for (int i = 0; i < 4; i++) {
        w[2 * i]     = __builtin_bit_cast(float, v[i] << 16);
        w[2 * i + 1] = __builtin_bit_cast(float, v[i] & 0xFFFF0000u);
    }
}

// ---------------------------------------------------------------- init map
__global__ __launch_bounds__(256) void init_map(uint4* __restrict__ m) {
    int i = blockIdx.x * 256 + threadIdx.x;        // 65536 uint4 = 1 MB
    uint4 v;
    v.x = v.y = v.z = v.w = 0xFFFFFFFFu;
    m[i] = v;
}

// ---------------------------------------------------------------- build map
__global__ __launch_bounds__(256) void build_map(const int* __restrict__ coords,
        int* __restrict__ map, int n) {
    int i = blockIdx.x * 256 + threadIdx.x;
    if (i < n) {
        int ix = coords[3 * i], iy = coords[3 * i + 1], iz = coords[3 * i + 2];
        map[(ix * GD + iy) * GD + iz] = i;         // coords unique (permutation)
    }
}

// ---------------------------------------------------------------- z pool (gather)
// No scatter kernel, no grid init: for each (x,y) column, roll a 7-deep z
// window gathering feats rows straight through the map. 32 lanes cover a full
// 512-B cell -> fully coalesced full-line writes of the dense z-pooled grid.
__global__ __launch_bounds__(256) void pool_z_gather(const float* __restrict__ feats,
        const int* __restrict__ map, u16* __restrict__ grid) {
    int chunk = threadIdx.x & 31;                  // 8 channels each
    int L = blockIdx.x * 8 + (threadIdx.x >> 5);   // 0..4095 = x*64+y
    const int* mrow = map + L * GD;
    u16* p = grid + (size_t)L * GD * GC + chunk * 8;

    float win[7][8];
#pragma unroll
    for (int s = 0; s < 7; s++)
#pragma unroll
        for (int cc = 0; cc < 8; cc++) win[s][cc] = -INFINITY;

#pragma unroll
    for (int t = 0; t < 3; t++) {                  // preload z=0..2 -> slots 3..5
        int mi = mrow[t];
        if (mi >= 0) {
            const float4* f4 = (const float4*)(feats + (size_t)mi * GC + chunk * 8);
            float4 a = f4[0], b = f4[1];
            win[t + 3][0] = bfval(a.x); win[t + 3][1] = bfval(a.y);
            win[t + 3][2] = bfval(a.z); win[t + 3][3] = bfval(a.w);
            win[t + 3][4] = bfval(b.x); win[t + 3][5] = bfval(b.y);
            win[t + 3][6] = bfval(b.z); win[t + 3][7] = bfval(b.w);
        }
    }

#pragma unroll
    for (int z = 0; z < 64; z++) {
        int slot = (z + 6) % 7;
        bool live = false;
        if (z + 3 < 64) {
            int mi = mrow[z + 3];
            if (mi >= 0) {
                live = true;
                const float4* f4 = (const float4*)(feats + (size_t)mi * GC + chunk * 8);
                float4 a = f4[0], b = f4[1];
                win[slot][0] = bfval(a.x); win[slot][1] = bfval(a.y);
                win[slot][2] = bfval(a.z); win[slot][3] = bfval(a.w);
                win[slot][4] = bfval(b.x); win[slot][5] = bfval(b.y);
                win[slot][6] = bfval(b.z); win[slot][7] = bfval(b.w);
            }
        }
        if (!live) {
#pragma unroll
            for (int cc = 0; cc < 8; cc++) win[slot][cc] = -INFINITY;
        }
        u32 q[4];
#pragma unroll
        for (int i = 0; i < 4; i++) {
            u32 halves[2];
#pragma unroll
            for (int hh = 0; hh < 2; hh++) {
                int c = 2 * i + hh;
                float m01 = fmaxf(win[0][c], win[1][c]);
                float m23 = fmaxf(win[2][c], win[3][c]);
                float m45 = fmaxf(win[4][c], win[5][c]);
                float m = fmaxf(fmaxf(m01, m23), fmaxf(m45, win[6][c]));
                halves[hh] = __builtin_bit_cast(u32, m);
            }
            q[i] = (halves[0] >> 16) | (halves[1] & 0xFFFF0000u);
        }
        *(uint4*)(p + (size_t)z * GC) = make_uint4(q[0], q[1], q[2], q[3]);
    }
}

// ---------------------------------------------------------------- y pool (in place)
// Proven rolling-window layout: full-cell coverage per 32 lanes, no barriers.
__global__ __launch_bounds__(256) void pool_pass_v(u16* __restrict__ grid,
        int mulA, int mulB, int strideCell) {
    int chunk = threadIdx.x & 31;
    int L = blockIdx.x * 8 + (threadIdx.x >> 5);   // 0..4095
    int a = L >> 6, b = L & 63;
    size_t baseEl = ((size_t)a * mulA + (size_t)b * mulB) * GC + chunk * 8;
    size_t stepEl = (size_t)strideCell * GC;
    u16* p = grid + baseEl;

    float win[7][8];
#pragma unroll
    for (int s = 0; s < 7; s++)
#pragma unroll
        for (int c = 0; c < 8; c++) win[s][c] = -INFINITY;

#pragma unroll
    for (int t = 0; t < 3; t++) {
        uint4 r = *(const uint4*)(p + (size_t)t * stepEl);
        unpack8(r, win[t + 3]);
    }

#pragma unroll
    for (int z = 0; z < 64; z++) {
        int slot = (z + 6) % 7;
        if (z + 3 < 64) {
            uint4 r = *(const uint4*)(p + (size_t)(z + 3) * stepEl);
            unpack8(r, win[slot]);
        } else {
#pragma unroll
            for (int c = 0; c < 8; c++) win[slot][c] = -INFINITY;
        }
        u32 q[4];
#pragma unroll
        for (int i = 0; i < 4; i++) {
            u32 halves[2];
#pragma unroll
            for (int hh = 0; hh < 2; hh++) {
                int c = 2 * i + hh;
                float m01 = fmaxf(win[0][c], win[1][c]);
                float m23 = fmaxf(win[2][c], win[3][c]);
                float m45 = fmaxf(win[4][c], win[5][c]);
                float m = fmaxf(fmaxf(m01, m23), fmaxf(m45, win[6][c]));
                halves[hh] = __builtin_bit_cast(u32, m);
            }
            q[i] = (halves[0] >> 16) | (halves[1] & 0xFFFF0000u);
        }
        *(uint4*)(p + (size_t)z * stepEl) = make_uint4(q[0], q[1], q[2], q[3]);
    }
}

// ---------------------------------------------------------------- x pool + compact
__global__ __launch_bounds__(256) void pool_x_compact(const u16* __restrict__ grid,
        const int* __restrict__ map, u16* __restrict__ P) {
    int chunk = threadIdx.x & 31;
    int L = blockIdx.x * 8 + (threadIdx.x >> 5);    // 0..4095 = y*64+z
    int cellBase = L;                               // y*GD+z at x=0
    const u16* p = grid + (size_t)cellBase * GC + chunk * 8;
    size_t stepEl = (size_t)(GD * GD) * GC;

    float win[7][8];
#pragma unroll
    for (int s = 0; s < 7; s++)
#pragma unroll
        for (int cc = 0; cc < 8; cc++) win[s][cc] = -INFINITY;

#pragma unroll
    for (int t = 0; t < 3; t++) {
        uint4 r = *(const uint4*)(p + (size_t)t * stepEl);
        unpack8(r, win[t + 3]);
    }

#pragma unroll
    for (int x = 0; x < 64; x++) {
        int slot = (x + 6) % 7;
        if (x + 3 < 64) {
            uint4 r = *(const uint4*)(p + (size_t)(x + 3) * stepEl);
            unpack8(r, win[slot]);
        } else {
#pragma unroll
            for (int cc = 0; cc < 8; cc++) win[slot][cc] = -INFINITY;
        }
        int mi = map[cellBase + x * GD * GD];       // uniform across 32 lanes
        if (mi >= 0) {
            u32 q[4];
#pragma unroll
            for (int iq = 0; iq < 4; iq++) {
                u32 halves[2];
#pragma unroll
                for (int hh = 0; hh < 2; hh++) {
                    int cc = 2 * iq + hh;
                    float m01 = fmaxf(win[0][cc], win[1][cc]);
                    float m23 = fmaxf(win[2][cc], win[3][cc]);
                    float m45 = fmaxf(win[4][cc], win[5][cc]);
                    float m = fmaxf(fmaxf(m01, m23), fmaxf(m45, win[6][cc]));
                    halves[hh] = __builtin_bit_cast(u32, m);
                }
                q[iq] = (halves[0] >> 16) | (halves[1] & 0xFFFF0000u);
            }
            *(uint4*)(P + (size_t)mi * GC + chunk * 8) = make_uint4(q[0], q[1], q[2], q[3]);
        }
    }
}

// ---------------------------------------------------------------- weight prep
__global__ __launch_bounds__(256) void prep_weights(const float* __restrict__ W1,
        const float* __restrict__ W2, u16* __restrict__ img1, u16* __restrict__ img2) {
    int t = blockIdx.x * 256 + threadIdx.x;   // 0..65535
    if (t < 32768) {
        int h = t >> 14, nn = (t >> 8) & 63, chunk = (t >> 3) & 31, j = t & 7;
        int k = chunk * 8 + j;
        img1[(h << 14) + nn * 256 + (((chunk ^ (nn & 7)) << 3) | j)] =
            f2bf_rne(W1[k * 128 + h * 64 + nn]);
    } else {
        int t2 = t - 32768;
        int h = t2 >> 14, nn = (t2 >> 7) & 127, chunk = (t2 >> 3) & 15, j = t2 & 7;
        int k = chunk * 8 + j;
        img2[(h << 14) + nn * 128 + (((chunk ^ (nn & 7)) << 3) | j)] =
            f2bf_rne(W2[k * 256 + h * 128 + nn]);
    }
}

// ---------------------------------------------------------------- GEMM1 (half-N)
__global__ __launch_bounds__(256, 4) void gemm1_kernel(const u16* __restrict__ P,
        const u16* __restrict__ img1, u16* __restrict__ H, int n, int nrb) {
    __shared__ __align__(16) u16 w1t[64 * 256];   // 32768 B; reused as hbuf
    int h = blockIdx.x >= nrb;
    int rb = blockIdx.x - (h ? nrb : 0);
    int tid = threadIdx.x;

    const uint4* src = (const uint4*)(img1 + (h << 14));
    uint4* dst = (uint4*)w1t;
#pragma unroll
    for (int i = 0; i < 8; i++) dst[i * 256 + tid] = src[i * 256 + tid];

    int wave = tid >> 6, lane = tid & 63, m16 = lane & 15, quad = lane >> 4;
    int row_a = rb * 64 + wave * 16 + m16;
    int ra = min(row_a, n - 1);
    const u16* yrow = P + (size_t)ra * GC;
    bf16x8 afr[8];
#pragma unroll
    for (int kk = 0; kk < 8; kk++)
        afr[kk] = *(const bf16x8*)(yrow + kk * 32 + quad * 8);
    __syncthreads();

    f32x4 acc[4];
#pragma unroll
    for (int t = 0; t < 4; t++) acc[t] = (f32x4){0.f, 0.f, 0.f, 0.f};
#pragma unroll
    for (int kk = 0; kk < 8; kk++) {
        int chunk = kk * 4 + quad;
#pragma unroll
        for (int t = 0; t < 4; t++) {
            int r = t * 16 + m16;
            bf16x8 b = *(const bf16x8*)&w1t[r * 256 + ((chunk ^ (r & 7)) << 3)];
            acc[t] = __builtin_amdgcn_mfma_f32_16x16x32_bf16(afr[kk], b, acc[t], 0, 0, 0);
        }
    }
    __syncthreads();   // w1t dead; reuse as hbuf

    u16* hbuf = w1t;
#pragma unroll
    for (int t = 0; t < 4; t++) {
        int col = t * 16 + m16;
        int c8 = col >> 3, j = col & 7;
#pragma unroll
        for (int rr = 0; rr < 4; rr++) {
            int row_l = wave * 16 + quad * 4 + rr;
            float hv = fmaxf(acc[t][rr], 0.0f);
            hbuf[row_l * 64 + (((c8 ^ (row_l & 7)) << 3) | j)] = f2bf_rne(hv);
        }
    }
    __syncthreads();
#pragma unroll
    for (int i = 0; i < 2; i++) {
        int cid = i * 256 + tid;            // 0..511 chunks of 8
        int row_l = cid >> 3, c8 = cid & 7;
        int grow = rb * 64 + row_l;
        if (grow < n) {
            bf16x8 v = *(const bf16x8*)&hbuf[row_l * 64 + ((c8 ^ (row_l & 7)) << 3)];
            *(bf16x8*)&H[(size_t)grow * 128 + h * 64 + c8 * 8] = v;
        }
    }
}

// ---------------------------------------------------------------- GEMM2 (half-N)
__global__ __launch_bounds__(256, 4) void gemm2_kernel(const u16* __restrict__ H,
        const u16* __restrict__ img2, const float* __restrict__ feats,
        float* __restrict__ out, int n, int nrb) {
    __shared__ __align__(16) char smem[64 * 140 * 4];   // 35840 B
    u16* w2t = (u16*)smem;
    float* zbuf = (float*)smem;
    int h = blockIdx.x >= nrb;
    int rb = blockIdx.x - (h ? nrb : 0);
    int tid = threadIdx.x;

    const uint4* src = (const uint4*)(img2 + (h << 14));
    uint4* dst = (uint4*)w2t;
#pragma unroll
    for (int i = 0; i < 8; i++) dst[i * 256 + tid] = src[i * 256 + tid];

    int wave = tid >> 6, lane = tid & 63, m16 = lane & 15, quad = lane >> 4;
    int row_a = rb * 64 + wave * 16 + m16;
    int ra = min(row_a, n - 1);
    const u16* hrow = H + (size_t)ra * 128;
    bf16x8 afr[4];
#pragma unroll
    for (int kk = 0; kk < 4; kk++)
        afr[kk] = *(const bf16x8*)(hrow + kk * 32 + quad * 8);
    __syncthreads();

    f32x4 acc[8];
#pragma unroll
    for (int t = 0; t < 8; t++) acc[t] = (f32x4){0.f, 0.f, 0.f, 0.f};
#pragma unroll
    for (int kk = 0; kk < 4; kk++) {
        int chunk = kk * 4 + quad;
#pragma unroll
        for (int t = 0; t < 8; t++) {
            int nn = t * 16 + m16;
            bf16x8 b = *(const bf16x8*)&w2t[nn * 128 + ((chunk ^ (nn & 7)) << 3)];
            acc[t] = __builtin_amdgcn_mfma_f32_16x16x32_bf16(afr[kk], b, acc[t], 0, 0, 0);
        }
    }
    __syncthreads();   // w2t dead; write logits into zbuf

#pragma unroll
    for (int t = 0; t < 8; t++) {
        int col = t * 16 + m16;
#pragma unroll
        for (int rr = 0; rr < 4; rr++) {
            int row_l = wave * 16 + quad * 4 + rr;
            zbuf[row_l * 140 + col] = acc[t][rr];
        }
    }
    __syncthreads();
#pragma unroll
    for (int i = 0; i < 8; i++) {
        int f = i * 256 + tid;              // 0..2047 float4s
        int row_l = f >> 5, c4 = f & 31;
        int grow = rb * 64 + row_l;
        if (grow < n) {
            f32x4 z = *(const f32x4*)&zbuf[row_l * 140 + c4 * 4];
            size_t o = (size_t)grow * 256 + h * 128 + c4 * 4;
            f32x4 ft = *(const f32x4*)&feats[o];
            f32x4 r;
#pragma unroll
            for (int c = 0; c < 4; c++)
                r[c] = ft[c] / (1.0f + __expf(-z[c]));
            *(f32x4*)&out[o] = r;
        }
    }
}

// ---------------------------------------------------------------- launch
extern "C" void kernel_launch(void* const* d_in, const int* in_sizes, int n_in,
                              void* d_out, int out_size, void* d_ws, size_t ws_size,
                              hipStream_t stream) {
    const float* feats = (const float*)d_in[0];
    const int* coords = (const int*)d_in[1];
    const float* W1 = (const float*)d_in[2];
    const float* W2 = (const float*)d_in[3];
    float* out = (float*)d_out;

    int n = in_sizes[1] / 3;                       // 100000 points

    size_t grid_bytes = (size_t)GD * GD * GD * GC * 2;          // 134,217,728
    size_t P_bytes = (size_t)n * GC * 2;                        //  51,200,000
    size_t H_bytes = (size_t)n * 128 * 2;                       //  25,600,000
    u16* grid = (u16*)d_ws;                                     // never initialized
    u16* P = (u16*)((char*)d_ws + grid_bytes);
    u16* H = (u16*)((char*)d_ws + grid_bytes + P_bytes);
    int* map = (int*)((char*)d_ws + grid_bytes + P_bytes + H_bytes);
    u16* img1 = (u16*)((char*)map + (size_t)GD * GD * GD * 4);  // +1 MB
    u16* img2 = img1 + 32768;

    init_map<<<256, 256, 0, stream>>>((uint4*)map);
    prep_weights<<<256, 256, 0, stream>>>(W1, W2, img1, img2);
    build_map<<<(n + 255) / 256, 256, 0, stream>>>(coords, map, n);

    pool_z_gather<<<512, 256, 0, stream>>>(feats, map, grid);      // z (gather)
    pool_pass_v<<<512, 256, 0, stream>>>(grid, GD * GD, 1, GD);    // y (in place)
    pool_x_compact<<<512, 256, 0, stream>>>(grid, map, P);         // x -> compact

    int nrb = (n + 63) / 64;
    gemm1_kernel<<<2 * nrb, 256, 0, stream>>>(P, img1, H, n, nrb);
    gemm2_kernel<<<2 * nrb, 256, 0, stream>>>(H, img2, feats, out, n, nrb);
}

// Round 3
// 375.129 us; speedup vs baseline: 1.6609x; 1.1948x over previous
//
#include <hip/hip_runtime.h>
#include <hip/hip_bf16.h>

#define GD 64
#define GC 256

typedef unsigned short u16;
typedef unsigned int u32;
typedef short bf16x8 __attribute__((ext_vector_type(8)));
typedef float f32x4 __attribute__((ext_vector_type(4)));

__device__ __forceinline__ u16 f2bf_rne(float f) {
    u32 u = __builtin_bit_cast(u32, f);
    u = (u + 0x7FFFu + ((u >> 16) & 1u)) >> 16;
    return (u16)u;
}

// round f32 to the exact bf16-representable value (RNE)
__device__ __forceinline__ float bfval(float f) {
    u32 u = __builtin_bit_cast(u32, f);
    u = (u + 0x7FFFu + ((u >> 16) & 1u)) & 0xFFFF0000u;
    return __builtin_bit_cast(float, u);
}

__device__ __forceinline__ void unpack8(uint4 r, float* w) {
    u32 v[4] = {r.x, r.y, r.z, r.w};
#pragma unroll
    for (int i = 0; i < 4; i++) {
        w[2 * i]     = __builtin_bit_cast(float, v[i] << 16);
        w[2 * i + 1] = __builtin_bit_cast(float, v[i] & 0xFFFF0000u);
    }
}

// max over the 7 window slots, packed to bf16 pairs (exact: values are bf16)
__device__ __forceinline__ uint4 maxpack(const float (&win)[7][8]) {
    u32 q[4];
#pragma unroll
    for (int i = 0; i < 4; i++) {
        u32 halves[2];
#pragma unroll
        for (int hh = 0; hh < 2; hh++) {
            int c = 2 * i + hh;
            float m01 = fmaxf(win[0][c], win[1][c]);
            float m23 = fmaxf(win[2][c], win[3][c]);
            float m45 = fmaxf(win[4][c], win[5][c]);
            float m = fmaxf(fmaxf(m01, m23), fmaxf(m45, win[6][c]));
            halves[hh] = __builtin_bit_cast(u32, m);
        }
        q[i] = (halves[0] >> 16) | (halves[1] & 0xFFFF0000u);
    }
    return make_uint4(q[0], q[1], q[2], q[3]);
}

// ---------------------------------------------------------------- init/build map
__global__ __launch_bounds__(256) void init_map(uint4* __restrict__ m) {
    int i = blockIdx.x * 256 + threadIdx.x;        // 65536 uint4 = 1 MB
    uint4 v;
    v.x = v.y = v.z = v.w = 0xFFFFFFFFu;
    m[i] = v;
}

__global__ __launch_bounds__(256) void build_map(const int* __restrict__ coords,
        int* __restrict__ map, int n) {
    int i = blockIdx.x * 256 + threadIdx.x;
    if (i < n) {
        int ix = coords[3 * i], iy = coords[3 * i + 1], iz = coords[3 * i + 2];
        map[(ix * GD + iy) * GD + iz] = i;         // coords unique (permutation)
    }
}

// ---------------------------------------------------------------- z pool (gather)
// Half-axis worker: outputs z in [Z0, Z0+32). Map row is pre-loaded in mv
// (lane l holds m[2l], m[2l+1]); every mi is a width-32 shuffle with a
// compile-time source lane, so feats loads have no upstream load dependency.
// All win[] indices are compile-time (Z0 is a template arg).
template<int Z0>
__device__ __forceinline__ void pool_z_half(const float* __restrict__ fb,
        int2 mv, u16* __restrict__ p) {
    float win[7][8];
#pragma unroll
    for (int s = 0; s < 7; s++)
#pragma unroll
        for (int c = 0; c < 8; c++) win[s][c] = -INFINITY;

#pragma unroll
    for (int t = 0; t < 6; t++) {                  // preload inputs w = Z0-3..Z0+2
        const int w = Z0 - 3 + t;
        if (w >= 0) {
            int mi = __shfl((w & 1) ? mv.y : mv.x, (w >> 1) & 31, 32);
            if (mi >= 0) {
                const float4* f4 = (const float4*)(fb + (size_t)mi * GC);
                float4 a = f4[0], b = f4[1];
                float* ws = win[(w + 3) % 7];
                ws[0] = bfval(a.x); ws[1] = bfval(a.y);
                ws[2] = bfval(a.z); ws[3] = bfval(a.w);
                ws[4] = bfval(b.x); ws[5] = bfval(b.y);
                ws[6] = bfval(b.z); ws[7] = bfval(b.w);
            }
        }
    }

#pragma unroll
    for (int d = 0; d < 32; d++) {
        const int z = Z0 + d, w = z + 3, slot = (w + 3) % 7;
        bool live = false;
        if (w < 64) {
            int mi = __shfl((w & 1) ? mv.y : mv.x, (w >> 1) & 31, 32);
            if (mi >= 0) {
                live = true;
                const float4* f4 = (const float4*)(fb + (size_t)mi * GC);
                float4 a = f4[0], b = f4[1];
                float* ws = win[slot];
                ws[0] = bfval(a.x); ws[1] = bfval(a.y);
                ws[2] = bfval(a.z); ws[3] = bfval(a.w);
                ws[4] = bfval(b.x); ws[5] = bfval(b.y);
                ws[6] = bfval(b.z); ws[7] = bfval(b.w);
            }
        }
        if (!live) {
#pragma unroll
            for (int c = 0; c < 8; c++) win[slot][c] = -INFINITY;
        }
        *(uint4*)(p + (size_t)z * GC) = maxpack(win);
    }
}

__global__ __launch_bounds__(256) void pool_z_gather(const float* __restrict__ feats,
        const int* __restrict__ map, u16* __restrict__ grid) {
    int lane = threadIdx.x & 31;
    int g = blockIdx.x * 8 + (threadIdx.x >> 5);   // 0..8191 (1024 blocks)
    int L = g & 4095;                              // x*64+y
    int2 mv = ((const int2*)(map + L * GD))[lane]; // lane l: m[2l], m[2l+1]
    const float* fb = feats + lane * 8;
    u16* p = grid + (size_t)L * GD * GC + lane * 8;
    if (g < 4096) pool_z_half<0>(fb, mv, p);       // block-uniform branch
    else          pool_z_half<32>(fb, mv, p);
}

// ---------------------------------------------------------------- dense line pool
// (y pass, out of place). Outputs axis index in [A0, A0+32), halo reads only.
template<int A0>
__device__ __forceinline__ void pool_line_dense(const u16* __restrict__ ip,
        u16* __restrict__ op, size_t stepEl) {
    float win[7][8];
#pragma unroll
    for (int s = 0; s < 7; s++)
#pragma unroll
        for (int c = 0; c < 8; c++) win[s][c] = -INFINITY;

#pragma unroll
    for (int t = 0; t < 6; t++) {
        const int w = A0 - 3 + t;
        if (w >= 0) {
            uint4 r = *(const uint4*)(ip + (size_t)w * stepEl);
            unpack8(r, win[(w + 3) % 7]);
        }
    }
#pragma unroll
    for (int d = 0; d < 32; d++) {
        const int a = A0 + d, w = a + 3, slot = (w + 3) % 7;
        if (w < 64) {
            uint4 r = *(const uint4*)(ip + (size_t)w * stepEl);
            unpack8(r, win[slot]);
        } else {
#pragma unroll
            for (int c = 0; c < 8; c++) win[slot][c] = -INFINITY;
        }
        *(uint4*)(op + (size_t)a * stepEl) = maxpack(win);
    }
}

__global__ __launch_bounds__(256) void pool_y(const u16* __restrict__ gin,
        u16* __restrict__ gout) {
    int lane = threadIdx.x & 31;
    int g = blockIdx.x * 8 + (threadIdx.x >> 5);   // 0..8191 (1024 blocks)
    int L = g & 4095;                              // x*64+z
    int x = L >> 6, z = L & 63;
    size_t base = ((size_t)x * GD * GD + z) * GC + lane * 8;
    size_t stepEl = (size_t)GD * GC;               // +1 in y
    if (g < 4096) pool_line_dense<0>(gin + base, gout + base, stepEl);
    else          pool_line_dense<32>(gin + base, gout + base, stepEl);
}

// ---------------------------------------------------------------- x pool + compact
// Map entries for the whole x-line pre-loaded into 2 regs/lane + shuffled;
// the store-gating mi never stalls on an in-loop load.
template<int X0>
__device__ __forceinline__ void pool_x_half(const u16* __restrict__ ip, size_t stepEl,
        int m0, int m1, u16* __restrict__ P, int chunkoff) {
    float win[7][8];
#pragma unroll
    for (int s = 0; s < 7; s++)
#pragma unroll
        for (int c = 0; c < 8; c++) win[s][c] = -INFINITY;

#pragma unroll
    for (int t = 0; t < 6; t++) {
        const int w = X0 - 3 + t;
        if (w >= 0) {
            uint4 r = *(const uint4*)(ip + (size_t)w * stepEl);
            unpack8(r, win[(w + 3) % 7]);
        }
    }
#pragma unroll
    for (int d = 0; d < 32; d++) {
        const int a = X0 + d, w = a + 3, slot = (w + 3) % 7;
        if (w < 64) {
            uint4 r = *(const uint4*)(ip + (size_t)w * stepEl);
            unpack8(r, win[slot]);
        } else {
#pragma unroll
            for (int c = 0; c < 8; c++) win[slot][c] = -INFINITY;
        }
        int mi = __shfl((a < 32) ? m0 : m1, a & 31, 32);
        if (mi >= 0)
            *(uint4*)(P + (size_t)mi * GC + chunkoff) = maxpack(win);
    }
}

__global__ __launch_bounds__(256) void pool_x_compact(const u16* __restrict__ gin,
        const int* __restrict__ map, u16* __restrict__ P) {
    int lane = threadIdx.x & 31;
    int g = blockIdx.x * 8 + (threadIdx.x >> 5);   // 0..8191 (1024 blocks)
    int L = g & 4095;                              // y*64+z
    int m0 = map[L + lane * GD * GD];              // x = lane
    int m1 = map[L + (lane + 32) * GD * GD];       // x = lane+32
    size_t base = (size_t)L * GC + lane * 8;
    size_t stepEl = (size_t)GD * GD * GC;          // +1 in x
    if (g < 4096) pool_x_half<0>(gin + base, stepEl, m0, m1, P, lane * 8);
    else          pool_x_half<32>(gin + base, stepEl, m0, m1, P, lane * 8);
}

// ---------------------------------------------------------------- weight prep
__global__ __launch_bounds__(256) void prep_weights(const float* __restrict__ W1,
        const float* __restrict__ W2, u16* __restrict__ img1, u16* __restrict__ img2) {
    int t = blockIdx.x * 256 + threadIdx.x;   // 0..65535
    if (t < 32768) {
        int h = t >> 14, nn = (t >> 8) & 63, chunk = (t >> 3) & 31, j = t & 7;
        int k = chunk * 8 + j;
        img1[(h << 14) + nn * 256 + (((chunk ^ (nn & 7)) << 3) | j)] =
            f2bf_rne(W1[k * 128 + h * 64 + nn]);
    } else {
        int t2 = t - 32768;
        int h = t2 >> 14, nn = (t2 >> 7) & 127, chunk = (t2 >> 3) & 15, j = t2 & 7;
        int k = chunk * 8 + j;
        img2[(h << 14) + nn * 128 + (((chunk ^ (nn & 7)) << 3) | j)] =
            f2bf_rne(W2[k * 256 + h * 128 + nn]);
    }
}

// ---------------------------------------------------------------- GEMM1 (half-N)
__global__ __launch_bounds__(256, 4) void gemm1_kernel(const u16* __restrict__ P,
        const u16* __restrict__ img1, u16* __restrict__ H, int n, int nrb) {
    __shared__ __align__(16) u16 w1t[64 * 256];   // 32768 B; reused as hbuf
    int h = blockIdx.x >= nrb;
    int rb = blockIdx.x - (h ? nrb : 0);
    int tid = threadIdx.x;

    const uint4* src = (const uint4*)(img1 + (h << 14));
    uint4* dst = (uint4*)w1t;
#pragma unroll
    for (int i = 0; i < 8; i++) dst[i * 256 + tid] = src[i * 256 + tid];

    int wave = tid >> 6, lane = tid & 63, m16 = lane & 15, quad = lane >> 4;
    int row_a = rb * 64 + wave * 16 + m16;
    int ra = min(row_a, n - 1);
    const u16* yrow = P + (size_t)ra * GC;
    bf16x8 afr[8];
#pragma unroll
    for (int kk = 0; kk < 8; kk++)
        afr[kk] = *(const bf16x8*)(yrow + kk * 32 + quad * 8);
    __syncthreads();

    f32x4 acc[4];
#pragma unroll
    for (int t = 0; t < 4; t++) acc[t] = (f32x4){0.f, 0.f, 0.f, 0.f};
#pragma unroll
    for (int kk = 0; kk < 8; kk++) {
        int chunk = kk * 4 + quad;
#pragma unroll
        for (int t = 0; t < 4; t++) {
            int r = t * 16 + m16;
            bf16x8 b = *(const bf16x8*)&w1t[r * 256 + ((chunk ^ (r & 7)) << 3)];
            acc[t] = __builtin_amdgcn_mfma_f32_16x16x32_bf16(afr[kk], b, acc[t], 0, 0, 0);
        }
    }
    __syncthreads();   // w1t dead; reuse as hbuf

    u16* hbuf = w1t;
#pragma unroll
    for (int t = 0; t < 4; t++) {
        int col = t * 16 + m16;
        int c8 = col >> 3, j = col & 7;
#pragma unroll
        for (int rr = 0; rr < 4; rr++) {
            int row_l = wave * 16 + quad * 4 + rr;
            float hv = fmaxf(acc[t][rr], 0.0f);
            hbuf[row_l * 64 + (((c8 ^ (row_l & 7)) << 3) | j)] = f2bf_rne(hv);
        }
    }
    __syncthreads();
#pragma unroll
    for (int i = 0; i < 2; i++) {
        int cid = i * 256 + tid;            // 0..511 chunks of 8
        int row_l = cid >> 3, c8 = cid & 7;
        int grow = rb * 64 + row_l;
        if (grow < n) {
            bf16x8 v = *(const bf16x8*)&hbuf[row_l * 64 + ((c8 ^ (row_l & 7)) << 3)];
            *(bf16x8*)&H[(size_t)grow * 128 + h * 64 + c8 * 8] = v;
        }
    }
}

// ---------------------------------------------------------------- GEMM2 (half-N)
__global__ __launch_bounds__(256, 4) void gemm2_kernel(const u16* __restrict__ H,
        const u16* __restrict__ img2, const float* __restrict__ feats,
        float* __restrict__ out, int n, int nrb) {
    __shared__ __align__(16) char smem[64 * 140 * 4];   // 35840 B
    u16* w2t = (u16*)smem;
    float* zbuf = (float*)smem;
    int h = blockIdx.x >= nrb;
    int rb = blockIdx.x - (h ? nrb : 0);
    int tid = threadIdx.x;

    const uint4* src = (const uint4*)(img2 + (h << 14));
    uint4* dst = (uint4*)w2t;
#pragma unroll
    for (int i = 0; i < 8; i++) dst[i * 256 + tid] = src[i * 256 + tid];

    int wave = tid >> 6, lane = tid & 63, m16 = lane & 15, quad = lane >> 4;
    int row_a = rb * 64 + wave * 16 + m16;
    int ra = min(row_a, n - 1);
    const u16* hrow = H + (size_t)ra * 128;
    bf16x8 afr[4];
#pragma unroll
    for (int kk = 0; kk < 4; kk++)
        afr[kk] = *(const bf16x8*)(hrow + kk * 32 + quad * 8);
    __syncthreads();

    f32x4 acc[8];
#pragma unroll
    for (int t = 0; t < 8; t++) acc[t] = (f32x4){0.f, 0.f, 0.f, 0.f};
#pragma unroll
    for (int kk = 0; kk < 4; kk++) {
        int chunk = kk * 4 + quad;
#pragma unroll
        for (int t = 0; t < 8; t++) {
            int nn = t * 16 + m16;
            bf16x8 b = *(const bf16x8*)&w2t[nn * 128 + ((chunk ^ (nn & 7)) << 3)];
            acc[t] = __builtin_amdgcn_mfma_f32_16x16x32_bf16(afr[kk], b, acc[t], 0, 0, 0);
        }
    }
    __syncthreads();   // w2t dead; write logits into zbuf

#pragma unroll
    for (int t = 0; t < 8; t++) {
        int col = t * 16 + m16;
#pragma unroll
        for (int rr = 0; rr < 4; rr++) {
            int row_l = wave * 16 + quad * 4 + rr;
            zbuf[row_l * 140 + col] = acc[t][rr];
        }
    }
    __syncthreads();
#pragma unroll
    for (int i = 0; i < 8; i++) {
        int f = i * 256 + tid;              // 0..2047 float4s
        int row_l = f >> 5, c4 = f & 31;
        int grow = rb * 64 + row_l;
        if (grow < n) {
            f32x4 z = *(const f32x4*)&zbuf[row_l * 140 + c4 * 4];
            size_t o = (size_t)grow * 256 + h * 128 + c4 * 4;
            f32x4 ft = *(const f32x4*)&feats[o];
            f32x4 r;
#pragma unroll
            for (int c = 0; c < 4; c++)
                r[c] = ft[c] / (1.0f + __expf(-z[c]));
            *(f32x4*)&out[o] = r;
        }
    }
}

// ---------------------------------------------------------------- launch
extern "C" void kernel_launch(void* const* d_in, const int* in_sizes, int n_in,
                              void* d_out, int out_size, void* d_ws, size_t ws_size,
                              hipStream_t stream) {
    const float* feats = (const float*)d_in[0];
    const int* coords = (const int*)d_in[1];
    const float* W1 = (const float*)d_in[2];
    const float* W2 = (const float*)d_in[3];
    float* out = (float*)d_out;

    int n = in_sizes[1] / 3;                       // 100000 points

    size_t grid_bytes = (size_t)GD * GD * GD * GC * 2;          // 134,217,728
    size_t P_bytes = (size_t)n * GC * 2;                        //  51,200,000
    size_t H_bytes = (size_t)n * 128 * 2;                       //  25,600,000
    u16* grid = (u16*)d_ws;                                     // never initialized
    u16* grid2 = (u16*)((char*)d_ws + grid_bytes);              // y-pass output
    u16* P = (u16*)((char*)d_ws + 2 * grid_bytes);
    u16* H = (u16*)((char*)d_ws + 2 * grid_bytes + P_bytes);
    int* map = (int*)((char*)d_ws + 2 * grid_bytes + P_bytes + H_bytes);
    u16* img1 = (u16*)((char*)map + (size_t)GD * GD * GD * 4);  // +1 MB
    u16* img2 = img1 + 32768;

    init_map<<<256, 256, 0, stream>>>((uint4*)map);
    prep_weights<<<256, 256, 0, stream>>>(W1, W2, img1, img2);
    build_map<<<(n + 255) / 256, 256, 0, stream>>>(coords, map, n);

    pool_z_gather<<<1024, 256, 0, stream>>>(feats, map, grid);     // z (gather, split)
    pool_y<<<1024, 256, 0, stream>>>(grid, grid2);                 // y (out of place, split)
    pool_x_compact<<<1024, 256, 0, stream>>>(grid2, map, P);       // x -> compact (split)

    int nrb = (n + 63) / 64;
    gemm1_kernel<<<2 * nrb, 256, 0, stream>>>(P, img1, H, n, nrb);
    gemm2_kernel<<<2 * nrb, 256, 0, stream>>>(H, img2, feats, out, n, nrb);
}